// Round 2
// baseline (744.597 us; speedup 1.0000x reference)
//
#include <hip/hip_runtime.h>

// GraphSAGE 3-layer, N=50000, E=1.6M, D=128.
// R7: src-tiled persistent aggregation — edge lists per node bucketed into 8
//     src-tiles (8192 nodes = 2MB of z, fits per-XCD L2); a persistent
//     exactly-resident grid (4096 waves) walks tiles in lockstep so gathers
//     become L2 hits. Half-wave-per-node, register accumulators, no LDS.
//     CSR build extended with per-(node,tile) offsets tp[n*8+t].

constexpr int N_NODES = 50000;
constexpr int N_EDGES = 1600000;
constexpr int D = 128;

constexpr int NBUCK = 392;                    // ceil(50176/128) node-range buckets
constexpr int BCAP  = 6144;                   // capacity per bucket (mean 4082)
constexpr int EPB   = 4096;                   // edges per block in count/scatter
constexpr int CS_BLOCKS = (N_EDGES + EPB - 1) / EPB;   // 391
constexpr int GC_STRIDE = 16;                 // 64B pad: 1 atomic counter per sector

constexpr int NT  = 8;                        // src tiles
constexpr int TSH = 13;                       // tile = src >> 13 (8192 nodes/tile)
constexpr int AGG_BLOCKS = 1024;              // x4 waves = 4096 waves, all resident
constexpr int PW = 14;                        // nodes per wave (7 pairs)

typedef __bf16 bf16x8 __attribute__((ext_vector_type(8)));
typedef float f32x4 __attribute__((ext_vector_type(4)));
union U8 { bf16x8 v; __bf16 e[8]; };

// ---------------- zero ----------------------------------------------------
__global__ void zero1(int* __restrict__ a, int n) {
    int i = blockIdx.x * blockDim.x + threadIdx.x;
    if (i < n) a[i] = 0;
}

// ---------------- bucket count + scatter ----------------------------------
// Per block: LDS hist over 392 buckets (dst>>7), reserve space per bucket with
// ONE padded global atomic, then write packed (dstlow<<16 | src) to bucketbuf.
__global__ __launch_bounds__(256) void bucket_count_scatter(
        const int* __restrict__ dst, const int* __restrict__ src,
        int* __restrict__ gcursor, int* __restrict__ bucketbuf) {
    __shared__ int hcnt[NBUCK];
    __shared__ int hbase[NBUCK];
    const int tid = threadIdx.x;
    for (int i = tid; i < NBUCK; i += 256) hcnt[i] = 0;
    __syncthreads();

    const int e0 = blockIdx.x * EPB;
    int d[16], lp[16];
    #pragma unroll
    for (int t = 0; t < 16; ++t) {
        const int e = e0 + t * 256 + tid;
        if (e < N_EDGES) {
            d[t] = dst[e];
            lp[t] = atomicAdd(&hcnt[d[t] >> 7], 1);   // LDS atomic, local pos
        } else {
            d[t] = 0; lp[t] = -1;
        }
    }
    __syncthreads();

    for (int i = tid; i < NBUCK; i += 256) {
        const int c = hcnt[i];
        hbase[i] = c ? atomicAdd(&gcursor[i * GC_STRIDE], c) : 0;  // 1/(blk,bucket)
    }
    __syncthreads();

    #pragma unroll
    for (int t = 0; t < 16; ++t) {
        const int e = e0 + t * 256 + tid;
        if (e < N_EDGES) {
            const int s  = src[e];
            const int bk = d[t] >> 7;
            const int p  = hbase[bk] + lp[t];
            if (p < BCAP)
                bucketbuf[bk * BCAP + p] = ((d[t] & 127) << 16) | s;
        }
    }
}

// ---------------- scan bucket totals -> bases ------------------------------
__global__ void bucket_scan(const int* __restrict__ gcursor,
                            int* __restrict__ bucket_base) {
    __shared__ int wsum[8], wpre[8];
    const int t = threadIdx.x;                // 512 threads, 8 waves
    const int lane = t & 63, w = t >> 6;
    int v = 0;
    if (t < NBUCK) { v = gcursor[t * GC_STRIDE]; if (v > BCAP) v = BCAP; }
    int x = v;
    #pragma unroll
    for (int off = 1; off < 64; off <<= 1) {
        int tt = __shfl_up(x, off, 64);
        if (lane >= off) x += tt;
    }
    if (lane == 63) wsum[w] = x;
    __syncthreads();
    if (t < 8) {
        int s = wsum[t], y = s;
        #pragma unroll
        for (int off = 1; off < 8; off <<= 1) {
            int tt = __shfl_up(y, off, 64);
            if (t >= off) y += tt;
        }
        wpre[t] = y - s;
    }
    __syncthreads();
    if (t < NBUCK) bucket_base[t] = wpre[w] + (x - v);
}

// ---------------- per-bucket CSR finalize (tile-aware) ---------------------
// One block per bucket: LDS hist of 128 nodes x 8 src-tiles -> tp[node*8+t]
// (global per-(node,tile) offsets) + inv_deg, then LDS-cursor scatter of esrc
// grouped by (node, tile) into the bucket's contiguous region.
__global__ __launch_bounds__(256) void bucket_csr(
        const int* __restrict__ gcursor, const int* __restrict__ bucket_base,
        const int* __restrict__ bucketbuf, int* __restrict__ tp,
        float* __restrict__ inv_deg, int* __restrict__ esrc) {
    __shared__ int h[1024];
    __shared__ int cur[1024];
    __shared__ int wsum[4], wpre[4];
    const int bk = blockIdx.x, tid = threadIdx.x;
    int cnt = gcursor[bk * GC_STRIDE];
    if (cnt > BCAP) cnt = BCAP;
    const int base = bucket_base[bk];
    #pragma unroll
    for (int k = 0; k < 4; ++k) h[tid * 4 + k] = 0;
    __syncthreads();

    const int* bb = bucketbuf + (size_t)bk * BCAP;
    for (int i = tid; i < cnt; i += 256) {
        const int p = bb[i];
        atomicAdd(&h[((p >> 16) << 3) | ((p & 0xFFFF) >> TSH)], 1);
    }
    __syncthreads();

    if (tid < 128) {
        int dg = 0;
        #pragma unroll
        for (int k = 0; k < 8; ++k) dg += h[tid * 8 + k];
        inv_deg[bk * 128 + tid] = 1.0f / fmaxf((float)dg, 1.0f);
    }

    // exclusive scan of 1024 counters (4 per thread)
    int v0 = h[tid * 4], v1 = h[tid * 4 + 1], v2 = h[tid * 4 + 2], v3 = h[tid * 4 + 3];
    const int s = v0 + v1 + v2 + v3;
    int x = s;
    const int lane = tid & 63, w = tid >> 6;
    #pragma unroll
    for (int off = 1; off < 64; off <<= 1) {
        int tt = __shfl_up(x, off, 64);
        if (lane >= off) x += tt;
    }
    if (lane == 63) wsum[w] = x;
    __syncthreads();
    if (tid == 0) {
        int a = 0;
        #pragma unroll
        for (int k = 0; k < 4; ++k) { wpre[k] = a; a += wsum[k]; }
    }
    __syncthreads();
    const int e0 = wpre[w] + (x - s);
    const int e1 = e0 + v0, e2 = e1 + v1, e3 = e2 + v2;
    cur[tid * 4] = e0; cur[tid * 4 + 1] = e1;
    cur[tid * 4 + 2] = e2; cur[tid * 4 + 3] = e3;
    // tp[bk*1024 + f] == tp[(bk*128 + f/8)*8 + f%8] — coalesced global write
    int* tpo = tp + (size_t)bk * 1024 + tid * 4;
    tpo[0] = base + e0; tpo[1] = base + e1; tpo[2] = base + e2; tpo[3] = base + e3;
    __syncthreads();

    for (int i = tid; i < cnt; i += 256) {
        const int p = bb[i];
        const int f = ((p >> 16) << 3) | ((p & 0xFFFF) >> TSH);
        esrc[base + atomicAdd(&cur[f], 1)] = p & 0xFFFF;
    }
}

// ---------------- pack W into MFMA B-fragment order, hi+lo ---------------
__global__ void pack_w(const float* __restrict__ w0, const float* __restrict__ w1,
                       const float* __restrict__ w2, const float* __restrict__ w3,
                       const float* __restrict__ w4, const float* __restrict__ w5,
                       __bf16* __restrict__ outbase) {
    const float* ws[6] = {w0, w1, w2, w3, w4, w5};
    const float* W = ws[blockIdx.y];
    __bf16* o = outbase + (size_t)blockIdx.y * 32768;
    int idx = blockIdx.x * 256 + threadIdx.x;   // 0..16383
    int t = idx & 7;
    int lane = (idx >> 3) & 63;
    int ks = (idx >> 9) & 3;
    int jt = idx >> 11;
    int j = jt * 16 + (lane & 15);
    int k = ks * 32 + (lane >> 4) * 8 + t;
    float w = W[j * D + k];
    __bf16 hi = (__bf16)w;
    o[idx] = hi;
    o[16384 + idx] = (__bf16)(w - (float)hi);
}

// ---------------- dual GEMM: y = h@Ws^T + b (fp32), z = h@Wn^T (bf16) ----
__global__ __launch_bounds__(256) void dual_gemm(
        const float* __restrict__ h, const __bf16* __restrict__ Bs,
        const __bf16* __restrict__ Bn, const float* __restrict__ bias,
        float* __restrict__ y_self, __bf16* __restrict__ z) {
    const int wave = threadIdx.x >> 6;
    const int lane = threadIdx.x & 63;
    const int tile = blockIdx.x * 4 + wave;
    if (tile >= N_NODES / 16) return;
    const int n0 = tile * 16;
    const int row = n0 + (lane & 15);
    const int koff = (lane >> 4) * 8;

    U8 ahi[4], alo[4];
    #pragma unroll
    for (int ks = 0; ks < 4; ++ks) {
        const float* p = h + (size_t)row * D + ks * 32 + koff;
        float f[8];
        *(f32x4*)&f[0] = *(const f32x4*)p;
        *(f32x4*)&f[4] = *(const f32x4*)(p + 4);
        #pragma unroll
        for (int t = 0; t < 8; ++t) {
            __bf16 hi = (__bf16)f[t];
            ahi[ks].e[t] = hi;
            alo[ks].e[t] = (__bf16)(f[t] - (float)hi);
        }
    }

    const int jcol = lane & 15;
    const int r0 = (lane >> 4) * 4;

    #pragma unroll 2
    for (int jt = 0; jt < 8; ++jt) {
        f32x4 accS = {0.f, 0.f, 0.f, 0.f};
        f32x4 accN = {0.f, 0.f, 0.f, 0.f};
        #pragma unroll
        for (int ks = 0; ks < 4; ++ks) {
            const size_t off = (((size_t)jt * 4 + ks) * 64 + lane) * 8;
            bf16x8 wsh = *(const bf16x8*)(Bs + off);
            bf16x8 wsl = *(const bf16x8*)(Bs + 16384 + off);
            bf16x8 wnh = *(const bf16x8*)(Bn + off);
            bf16x8 wnl = *(const bf16x8*)(Bn + 16384 + off);
            accS = __builtin_amdgcn_mfma_f32_16x16x32_bf16(ahi[ks].v, wsh, accS, 0, 0, 0);
            accS = __builtin_amdgcn_mfma_f32_16x16x32_bf16(alo[ks].v, wsh, accS, 0, 0, 0);
            accS = __builtin_amdgcn_mfma_f32_16x16x32_bf16(ahi[ks].v, wsl, accS, 0, 0, 0);
            accN = __builtin_amdgcn_mfma_f32_16x16x32_bf16(ahi[ks].v, wnh, accN, 0, 0, 0);
            accN = __builtin_amdgcn_mfma_f32_16x16x32_bf16(alo[ks].v, wnh, accN, 0, 0, 0);
            accN = __builtin_amdgcn_mfma_f32_16x16x32_bf16(ahi[ks].v, wnl, accN, 0, 0, 0);
        }
        const int j = jt * 16 + jcol;
        const float bj = bias[j];
        #pragma unroll
        for (int r = 0; r < 4; ++r) {
            const size_t n = n0 + r0 + r;
            y_self[n * D + j] = accS[r] + bj;
            z[n * D + j] = (__bf16)accN[r];
        }
    }
}

// ---------------- persistent tiled aggregation ----------------------------
// 4096 waves, all co-resident; tile-major loop keeps the active 2MB z-tile
// in every XCD's L2. Half-wave per node: 32 lanes x 8B = one 256B z row per
// load. Each lane owns cols 4*hl..4*hl+3 of its half's nodes; accumulators
// live in registers (7 pairs x f32x4 = 28 VGPRs); no LDS, no shuffles.
__global__ __launch_bounds__(256, 4) void agg_tiled(
        const __bf16* __restrict__ z, const int* __restrict__ esrc,
        const int* __restrict__ tp, const float* __restrict__ inv_deg,
        const float* __restrict__ y_self, float* __restrict__ out, int do_relu) {
    const int wid = (blockIdx.x * 256 + threadIdx.x) >> 6;   // 0..4095
    const int lane = threadIdx.x & 63;
    const int half = lane >> 5;
    const int hl = lane & 31;

    f32x4 acc[7];
    #pragma unroll
    for (int i = 0; i < 7; ++i) acc[i] = (f32x4){0.f, 0.f, 0.f, 0.f};

    const char* zc = (const char*)z;
    const unsigned coff = (unsigned)hl * 8u;

    for (int t = 0; t < NT; ++t) {
        #pragma unroll
        for (int pi = 0; pi < 7; ++pi) {
            const int n = (pi * 2 + half) * 4096 + wid;   // strided for balance
            int r0 = 0, r1 = 0;
            if (n < N_NODES) {
                r0 = tp[n * NT + t];
                r1 = tp[n * NT + t + 1];
            }
            int e = r0;
            while (__any(e < r1)) {
                if (e < r1) {
                    const unsigned s = (unsigned)esrc[e];
                    const uint2 v = *(const uint2*)(zc + (size_t)s * 256u + coff);
                    acc[pi][0] += __uint_as_float(v.x << 16);
                    acc[pi][1] += __uint_as_float(v.x & 0xffff0000u);
                    acc[pi][2] += __uint_as_float(v.y << 16);
                    acc[pi][3] += __uint_as_float(v.y & 0xffff0000u);
                }
                if (e + 1 < r1) {
                    const unsigned s = (unsigned)esrc[e + 1];
                    const uint2 v = *(const uint2*)(zc + (size_t)s * 256u + coff);
                    acc[pi][0] += __uint_as_float(v.x << 16);
                    acc[pi][1] += __uint_as_float(v.x & 0xffff0000u);
                    acc[pi][2] += __uint_as_float(v.y << 16);
                    acc[pi][3] += __uint_as_float(v.y & 0xffff0000u);
                }
                e += 2;
            }
        }
    }

    #pragma unroll
    for (int pi = 0; pi < 7; ++pi) {
        const int n = (pi * 2 + half) * 4096 + wid;
        if (n < N_NODES) {
            const float idg = inv_deg[n];
            const float* yp = y_self + (size_t)n * D + hl * 4;
            const f32x4 y = *(const f32x4*)yp;
            f32x4 o;
            #pragma unroll
            for (int k = 0; k < 4; ++k) o[k] = y[k] + acc[pi][k] * idg;
            if (do_relu) {
                #pragma unroll
                for (int k = 0; k < 4; ++k) o[k] = fmaxf(o[k], 0.f);
            }
            *(f32x4*)(out + (size_t)n * D + hl * 4) = o;
        }
    }
}

extern "C" void kernel_launch(void* const* d_in, const int* in_sizes, int n_in,
                              void* d_out, int out_size, void* d_ws, size_t ws_size,
                              hipStream_t stream) {
    const float* x   = (const float*)d_in[0];
    const int* src   = (const int*)d_in[1];
    const int* dst   = (const int*)d_in[2];
    const float* Wn1 = (const float*)d_in[3];
    const float* Ws1 = (const float*)d_in[4];
    const float* b1  = (const float*)d_in[5];
    const float* Wn2 = (const float*)d_in[6];
    const float* Ws2 = (const float*)d_in[7];
    const float* b2  = (const float*)d_in[8];
    const float* Wn3 = (const float*)d_in[9];
    const float* Ws3 = (const float*)d_in[10];
    const float* b3  = (const float*)d_in[11];
    float* out = (float*)d_out;

    char* w = (char*)d_ws;
    float* inv_deg     = (float*)w;             w += 50176 * 4;
    int* tp            = (int*)w;               w += (size_t)NBUCK * 1024 * 4;  // per-(node,tile)
    int* gcursor       = (int*)w;               w += NBUCK * GC_STRIDE * 4;
    int* bucket_base   = (int*)w;               w += 512 * 4;
    int* esrc          = (int*)w;               w += (size_t)N_EDGES * 4;
    __bf16* Bpk        = (__bf16*)w;            w += 6 * 32768 * 2;
    __bf16* zbuf       = (__bf16*)w;            w += (size_t)50176 * D * 2;
    float* bufA        = (float*)w;             // N*D floats

    // bucketbuf (392*6144*4B = 9.63MB) aliases zbuf (12.8MB): consumed by
    // bucket_csr before dual_gemm first writes zbuf (stream-ordered).
    int* bucketbuf = (int*)zbuf;

    const __bf16* PWs1 = Bpk + 0 * 32768, *PWn1 = Bpk + 1 * 32768;
    const __bf16* PWs2 = Bpk + 2 * 32768, *PWn2 = Bpk + 3 * 32768;
    const __bf16* PWs3 = Bpk + 4 * 32768, *PWn3 = Bpk + 5 * 32768;

    // ---- CSR build (bucketed, tile-aware) ----
    zero1<<<(NBUCK * GC_STRIDE + 255) / 256, 256, 0, stream>>>(gcursor, NBUCK * GC_STRIDE);
    bucket_count_scatter<<<CS_BLOCKS, 256, 0, stream>>>(dst, src, gcursor, bucketbuf);
    bucket_scan<<<1, 512, 0, stream>>>(gcursor, bucket_base);
    bucket_csr<<<NBUCK, 256, 0, stream>>>(gcursor, bucket_base, bucketbuf,
                                          tp, inv_deg, esrc);

    // ---- pack weights (order: Ws1,Wn1,Ws2,Wn2,Ws3,Wn3) ----
    pack_w<<<dim3(64, 6), 256, 0, stream>>>(Ws1, Wn1, Ws2, Wn2, Ws3, Wn3, Bpk);

    const int ggrid = (N_NODES / 16 + 3) / 4;   // 782 blocks x 4 waves

    // layer 1: h=x -> bufA (relu)
    dual_gemm<<<ggrid, 256, 0, stream>>>(x, PWs1, PWn1, b1, bufA, zbuf);
    agg_tiled<<<AGG_BLOCKS, 256, 0, stream>>>(zbuf, esrc, tp, inv_deg, bufA, bufA, 1);

    // layer 2: h=bufA -> d_out (relu)
    dual_gemm<<<ggrid, 256, 0, stream>>>(bufA, PWs2, PWn2, b2, out, zbuf);
    agg_tiled<<<AGG_BLOCKS, 256, 0, stream>>>(zbuf, esrc, tp, inv_deg, out, out, 1);

    // layer 3: h=d_out -> d_out (no relu), y_self staged in bufA
    dual_gemm<<<ggrid, 256, 0, stream>>>(out, PWs3, PWn3, b3, bufA, zbuf);
    agg_tiled<<<AGG_BLOCKS, 256, 0, stream>>>(zbuf, esrc, tp, inv_deg, bufA, out, 0);
}

// Round 3
// 452.397 us; speedup vs baseline: 1.6459x; 1.6459x over previous
//
#include <hip/hip_runtime.h>

// GraphSAGE 3-layer, N=50000, E=1.6M, D=128.
// R8: tile-sorted edge lists (NT=4 even src-tiles of 12500 nodes = 3.2MB z,
//     fits per-XCD L2) + R5-style high-MLP gather: one 16-lane quarter-wave
//     per node, 4 independent edge loads in flight, uniform control flow.
//     Fixes R7's latency-bound regression (2-deep loads, __any loop, 4096
//     waves) while keeping its L2-locality win (z fetch 133->~50MB).

constexpr int N_NODES = 50000;
constexpr int N_EDGES = 1600000;
constexpr int D = 128;

constexpr int NBUCK = 392;                    // ceil(50176/128) node-range buckets
constexpr int BCAP  = 6144;                   // capacity per bucket (mean 4082)
constexpr int EPB   = 4096;                   // edges per block in count/scatter
constexpr int CS_BLOCKS = (N_EDGES + EPB - 1) / EPB;   // 391
constexpr int GC_STRIDE = 16;                 // 64B pad: 1 atomic counter per sector

constexpr int NT   = 4;                       // src tiles (even size)
constexpr unsigned TDIV = 12500u;             // tile = src / 12500 -> 0..3

typedef __bf16 bf16x8 __attribute__((ext_vector_type(8)));
typedef float f32x4 __attribute__((ext_vector_type(4)));
union U8 { bf16x8 v; __bf16 e[8]; };

// ---------------- zero ----------------------------------------------------
__global__ void zero1(int* __restrict__ a, int n) {
    int i = blockIdx.x * blockDim.x + threadIdx.x;
    if (i < n) a[i] = 0;
}

// ---------------- bucket count + scatter ----------------------------------
// Per block: LDS hist over 392 buckets (dst>>7), reserve space per bucket with
// ONE padded global atomic, then write packed (dstlow<<16 | src) to bucketbuf.
__global__ __launch_bounds__(256) void bucket_count_scatter(
        const int* __restrict__ dst, const int* __restrict__ src,
        int* __restrict__ gcursor, int* __restrict__ bucketbuf) {
    __shared__ int hcnt[NBUCK];
    __shared__ int hbase[NBUCK];
    const int tid = threadIdx.x;
    for (int i = tid; i < NBUCK; i += 256) hcnt[i] = 0;
    __syncthreads();

    const int e0 = blockIdx.x * EPB;
    int d[16], lp[16];
    #pragma unroll
    for (int t = 0; t < 16; ++t) {
        const int e = e0 + t * 256 + tid;
        if (e < N_EDGES) {
            d[t] = dst[e];
            lp[t] = atomicAdd(&hcnt[d[t] >> 7], 1);   // LDS atomic, local pos
        } else {
            d[t] = 0; lp[t] = -1;
        }
    }
    __syncthreads();

    for (int i = tid; i < NBUCK; i += 256) {
        const int c = hcnt[i];
        hbase[i] = c ? atomicAdd(&gcursor[i * GC_STRIDE], c) : 0;  // 1/(blk,bucket)
    }
    __syncthreads();

    #pragma unroll
    for (int t = 0; t < 16; ++t) {
        const int e = e0 + t * 256 + tid;
        if (e < N_EDGES) {
            const int s  = src[e];
            const int bk = d[t] >> 7;
            const int p  = hbase[bk] + lp[t];
            if (p < BCAP)
                bucketbuf[bk * BCAP + p] = ((d[t] & 127) << 16) | s;
        }
    }
}

// ---------------- scan bucket totals -> bases ------------------------------
__global__ void bucket_scan(const int* __restrict__ gcursor,
                            int* __restrict__ bucket_base) {
    __shared__ int wsum[8], wpre[8];
    const int t = threadIdx.x;                // 512 threads, 8 waves
    const int lane = t & 63, w = t >> 6;
    int v = 0;
    if (t < NBUCK) { v = gcursor[t * GC_STRIDE]; if (v > BCAP) v = BCAP; }
    int x = v;
    #pragma unroll
    for (int off = 1; off < 64; off <<= 1) {
        int tt = __shfl_up(x, off, 64);
        if (lane >= off) x += tt;
    }
    if (lane == 63) wsum[w] = x;
    __syncthreads();
    if (t < 8) {
        int s = wsum[t], y = s;
        #pragma unroll
        for (int off = 1; off < 8; off <<= 1) {
            int tt = __shfl_up(y, off, 64);
            if (t >= off) y += tt;
        }
        wpre[t] = y - s;
    }
    __syncthreads();
    if (t < NBUCK) bucket_base[t] = wpre[w] + (x - v);
}

// ---------------- per-bucket CSR finalize (tile-aware, NT=4) ---------------
// One block per bucket: LDS hist of 128 nodes x 4 src-tiles -> tp[node*4+t]
// (global per-(node,tile) offsets) + inv_deg, then LDS-cursor scatter of esrc
// grouped by (node, tile) into the bucket's contiguous region. Result: esrc
// globally sorted by (dst, src-tile).
__global__ __launch_bounds__(256) void bucket_csr(
        const int* __restrict__ gcursor, const int* __restrict__ bucket_base,
        const int* __restrict__ bucketbuf, int* __restrict__ tp,
        float* __restrict__ inv_deg, int* __restrict__ esrc) {
    __shared__ int h[512];
    __shared__ int cur[512];
    __shared__ int wsum[4], wpre[4];
    const int bk = blockIdx.x, tid = threadIdx.x;
    int cnt = gcursor[bk * GC_STRIDE];
    if (cnt > BCAP) cnt = BCAP;
    const int base = bucket_base[bk];
    h[tid * 2] = 0; h[tid * 2 + 1] = 0;
    __syncthreads();

    const int* bb = bucketbuf + (size_t)bk * BCAP;
    for (int i = tid; i < cnt; i += 256) {
        const int p = bb[i];
        atomicAdd(&h[((p >> 16) << 2) | (unsigned)((p & 0xFFFF) / TDIV)], 1);
    }
    __syncthreads();

    if (tid < 128) {
        const int dg = h[tid * 4] + h[tid * 4 + 1] + h[tid * 4 + 2] + h[tid * 4 + 3];
        inv_deg[bk * 128 + tid] = 1.0f / fmaxf((float)dg, 1.0f);
    }

    // exclusive scan of 512 counters (2 per thread)
    const int v0 = h[tid * 2], v1 = h[tid * 2 + 1];
    const int s = v0 + v1;
    int x = s;
    const int lane = tid & 63, w = tid >> 6;
    #pragma unroll
    for (int off = 1; off < 64; off <<= 1) {
        int tt = __shfl_up(x, off, 64);
        if (lane >= off) x += tt;
    }
    if (lane == 63) wsum[w] = x;
    __syncthreads();
    if (tid == 0) {
        int a = 0;
        #pragma unroll
        for (int k = 0; k < 4; ++k) { wpre[k] = a; a += wsum[k]; }
    }
    __syncthreads();
    const int e0 = wpre[w] + (x - s);
    cur[tid * 2] = e0;
    cur[tid * 2 + 1] = e0 + v0;
    int* tpo = tp + (size_t)bk * 512 + tid * 2;
    tpo[0] = base + e0;
    tpo[1] = base + e0 + v0;
    __syncthreads();

    for (int i = tid; i < cnt; i += 256) {
        const int p = bb[i];
        const int f = ((p >> 16) << 2) | (unsigned)((p & 0xFFFF) / TDIV);
        esrc[base + atomicAdd(&cur[f], 1)] = p & 0xFFFF;
    }
}

// ---------------- pack W into MFMA B-fragment order, hi+lo ---------------
__global__ void pack_w(const float* __restrict__ w0, const float* __restrict__ w1,
                       const float* __restrict__ w2, const float* __restrict__ w3,
                       const float* __restrict__ w4, const float* __restrict__ w5,
                       __bf16* __restrict__ outbase) {
    const float* ws[6] = {w0, w1, w2, w3, w4, w5};
    const float* W = ws[blockIdx.y];
    __bf16* o = outbase + (size_t)blockIdx.y * 32768;
    int idx = blockIdx.x * 256 + threadIdx.x;   // 0..16383
    int t = idx & 7;
    int lane = (idx >> 3) & 63;
    int ks = (idx >> 9) & 3;
    int jt = idx >> 11;
    int j = jt * 16 + (lane & 15);
    int k = ks * 32 + (lane >> 4) * 8 + t;
    float w = W[j * D + k];
    __bf16 hi = (__bf16)w;
    o[idx] = hi;
    o[16384 + idx] = (__bf16)(w - (float)hi);
}

// ---------------- dual GEMM: y = h@Ws^T + b (fp32), z = h@Wn^T (bf16) ----
__global__ __launch_bounds__(256) void dual_gemm(
        const float* __restrict__ h, const __bf16* __restrict__ Bs,
        const __bf16* __restrict__ Bn, const float* __restrict__ bias,
        float* __restrict__ y_self, __bf16* __restrict__ z) {
    const int wave = threadIdx.x >> 6;
    const int lane = threadIdx.x & 63;
    const int tile = blockIdx.x * 4 + wave;
    if (tile >= N_NODES / 16) return;
    const int n0 = tile * 16;
    const int row = n0 + (lane & 15);
    const int koff = (lane >> 4) * 8;

    U8 ahi[4], alo[4];
    #pragma unroll
    for (int ks = 0; ks < 4; ++ks) {
        const float* p = h + (size_t)row * D + ks * 32 + koff;
        float f[8];
        *(f32x4*)&f[0] = *(const f32x4*)p;
        *(f32x4*)&f[4] = *(const f32x4*)(p + 4);
        #pragma unroll
        for (int t = 0; t < 8; ++t) {
            __bf16 hi = (__bf16)f[t];
            ahi[ks].e[t] = hi;
            alo[ks].e[t] = (__bf16)(f[t] - (float)hi);
        }
    }

    const int jcol = lane & 15;
    const int r0 = (lane >> 4) * 4;

    #pragma unroll 2
    for (int jt = 0; jt < 8; ++jt) {
        f32x4 accS = {0.f, 0.f, 0.f, 0.f};
        f32x4 accN = {0.f, 0.f, 0.f, 0.f};
        #pragma unroll
        for (int ks = 0; ks < 4; ++ks) {
            const size_t off = (((size_t)jt * 4 + ks) * 64 + lane) * 8;
            bf16x8 wsh = *(const bf16x8*)(Bs + off);
            bf16x8 wsl = *(const bf16x8*)(Bs + 16384 + off);
            bf16x8 wnh = *(const bf16x8*)(Bn + off);
            bf16x8 wnl = *(const bf16x8*)(Bn + 16384 + off);
            accS = __builtin_amdgcn_mfma_f32_16x16x32_bf16(ahi[ks].v, wsh, accS, 0, 0, 0);
            accS = __builtin_amdgcn_mfma_f32_16x16x32_bf16(alo[ks].v, wsh, accS, 0, 0, 0);
            accS = __builtin_amdgcn_mfma_f32_16x16x32_bf16(ahi[ks].v, wsl, accS, 0, 0, 0);
            accN = __builtin_amdgcn_mfma_f32_16x16x32_bf16(ahi[ks].v, wnh, accN, 0, 0, 0);
            accN = __builtin_amdgcn_mfma_f32_16x16x32_bf16(alo[ks].v, wnh, accN, 0, 0, 0);
            accN = __builtin_amdgcn_mfma_f32_16x16x32_bf16(ahi[ks].v, wnl, accN, 0, 0, 0);
        }
        const int j = jt * 16 + jcol;
        const float bj = bias[j];
        #pragma unroll
        for (int r = 0; r < 4; ++r) {
            const size_t n = n0 + r0 + r;
            y_self[n * D + j] = accS[r] + bj;
            z[n * D + j] = (__bf16)accN[r];
        }
    }
}

// ---------------- tile-phased aggregation (high-MLP) ----------------------
// One 16-lane quarter-wave per node: lane c loads bytes [c*16, c*16+16) of
// each 256B z row and owns output cols c*8..c*8+7 — no cross-lane reduce.
// Edges are tile-sorted; per tile-segment, 4 independent loads in flight.
// Grid = 3125 blocks x 16 quarters = exactly 50000 nodes; most blocks
// co-resident and phase-aligned so concurrent gathers hit the same 3.2MB
// z-tile in each XCD's L2.
__global__ __launch_bounds__(256) void agg_tiled(
        const __bf16* __restrict__ z, const int* __restrict__ esrc,
        const int* __restrict__ tp, const float* __restrict__ inv_deg,
        const float* __restrict__ y_self, float* __restrict__ out, int do_relu) {
    const int n = (blockIdx.x * 256 + threadIdx.x) >> 4;   // node, 0..49999
    const int c = threadIdx.x & 15;

    float acc[8] = {0.f, 0.f, 0.f, 0.f, 0.f, 0.f, 0.f, 0.f};
    const char* zc = (const char*)z;
    const unsigned coff = (unsigned)c * 16u;

    int r0 = tp[n * NT];
    for (int t = 0; t < NT; ++t) {
        const int r1 = tp[n * NT + t + 1];
        for (int e = r0; e < r1; e += 4) {
            #pragma unroll
            for (int k = 0; k < 4; ++k) {
                if (e + k < r1) {
                    const unsigned s = (unsigned)esrc[e + k];
                    U8 v;
                    v.v = *(const bf16x8*)(zc + (size_t)s * 256u + coff);
                    #pragma unroll
                    for (int j = 0; j < 8; ++j) acc[j] += (float)v.e[j];
                }
            }
        }
        r0 = r1;
        __syncthreads();   // keep block's quarters phase-aligned per tile
    }

    const float idg = inv_deg[n];
    const float* yp = y_self + (size_t)n * D + c * 8;
    const f32x4 y0 = *(const f32x4*)yp;
    const f32x4 y1 = *(const f32x4*)(yp + 4);
    float o[8];
    #pragma unroll
    for (int k = 0; k < 4; ++k) o[k] = y0[k] + acc[k] * idg;
    #pragma unroll
    for (int k = 0; k < 4; ++k) o[4 + k] = y1[k] + acc[4 + k] * idg;
    if (do_relu) {
        #pragma unroll
        for (int k = 0; k < 8; ++k) o[k] = fmaxf(o[k], 0.f);
    }
    float* op = out + (size_t)n * D + c * 8;
    *(f32x4*)op = *(f32x4*)&o[0];
    *(f32x4*)(op + 4) = *(f32x4*)&o[4];
}

extern "C" void kernel_launch(void* const* d_in, const int* in_sizes, int n_in,
                              void* d_out, int out_size, void* d_ws, size_t ws_size,
                              hipStream_t stream) {
    const float* x   = (const float*)d_in[0];
    const int* src   = (const int*)d_in[1];
    const int* dst   = (const int*)d_in[2];
    const float* Wn1 = (const float*)d_in[3];
    const float* Ws1 = (const float*)d_in[4];
    const float* b1  = (const float*)d_in[5];
    const float* Wn2 = (const float*)d_in[6];
    const float* Ws2 = (const float*)d_in[7];
    const float* b2  = (const float*)d_in[8];
    const float* Wn3 = (const float*)d_in[9];
    const float* Ws3 = (const float*)d_in[10];
    const float* b3  = (const float*)d_in[11];
    float* out = (float*)d_out;

    char* w = (char*)d_ws;
    float* inv_deg     = (float*)w;             w += 50176 * 4;
    int* tp            = (int*)w;               w += (size_t)NBUCK * 512 * 4;  // per-(node,tile)
    int* gcursor       = (int*)w;               w += NBUCK * GC_STRIDE * 4;
    int* bucket_base   = (int*)w;               w += 512 * 4;
    int* esrc          = (int*)w;               w += (size_t)N_EDGES * 4;
    __bf16* Bpk        = (__bf16*)w;            w += 6 * 32768 * 2;
    __bf16* zbuf       = (__bf16*)w;            w += (size_t)50176 * D * 2;
    float* bufA        = (float*)w;             // N*D floats

    // bucketbuf (392*6144*4B = 9.63MB) aliases zbuf (12.8MB): consumed by
    // bucket_csr before dual_gemm first writes zbuf (stream-ordered).
    int* bucketbuf = (int*)zbuf;

    const __bf16* PWs1 = Bpk + 0 * 32768, *PWn1 = Bpk + 1 * 32768;
    const __bf16* PWs2 = Bpk + 2 * 32768, *PWn2 = Bpk + 3 * 32768;
    const __bf16* PWs3 = Bpk + 4 * 32768, *PWn3 = Bpk + 5 * 32768;

    // ---- CSR build (bucketed, tile-sorted) ----
    zero1<<<(NBUCK * GC_STRIDE + 255) / 256, 256, 0, stream>>>(gcursor, NBUCK * GC_STRIDE);
    bucket_count_scatter<<<CS_BLOCKS, 256, 0, stream>>>(dst, src, gcursor, bucketbuf);
    bucket_scan<<<1, 512, 0, stream>>>(gcursor, bucket_base);
    bucket_csr<<<NBUCK, 256, 0, stream>>>(gcursor, bucket_base, bucketbuf,
                                          tp, inv_deg, esrc);

    // ---- pack weights (order: Ws1,Wn1,Ws2,Wn2,Ws3,Wn3) ----
    pack_w<<<dim3(64, 6), 256, 0, stream>>>(Ws1, Wn1, Ws2, Wn2, Ws3, Wn3, Bpk);

    const int ggrid = (N_NODES / 16 + 3) / 4;   // 782 blocks x 4 waves
    const int agrid = N_NODES * 16 / 256;       // 3125 blocks, 16 quarters each

    // layer 1: h=x -> bufA (relu)
    dual_gemm<<<ggrid, 256, 0, stream>>>(x, PWs1, PWn1, b1, bufA, zbuf);
    agg_tiled<<<agrid, 256, 0, stream>>>(zbuf, esrc, tp, inv_deg, bufA, bufA, 1);

    // layer 2: h=bufA -> d_out (relu)
    dual_gemm<<<ggrid, 256, 0, stream>>>(bufA, PWs2, PWn2, b2, out, zbuf);
    agg_tiled<<<agrid, 256, 0, stream>>>(zbuf, esrc, tp, inv_deg, out, out, 1);

    // layer 3: h=d_out -> d_out (no relu), y_self staged in bufA
    dual_gemm<<<ggrid, 256, 0, stream>>>(out, PWs3, PWn3, b3, bufA, zbuf);
    agg_tiled<<<agrid, 256, 0, stream>>>(zbuf, esrc, tp, inv_deg, bufA, out, 0);
}

// Round 4
// 378.945 us; speedup vs baseline: 1.9649x; 1.1938x over previous
//
#include <hip/hip_runtime.h>

// GraphSAGE 3-layer, N=50000, E=1.6M, D=128.
// R9: R5's proven agg_add loop (wave/node, wave-uniform bounds, 16 loads in
//     flight) fed with TILE-SORTED edge lists: esrc sorted by (dst, src>>13).
//     Resident waves consume tiles in the same order -> instantaneous z
//     working set shrinks from 12.8MB to ~1-2 tiles (2-4MB, fits per-XCD L2)
//     with ZERO change to the agg instruction stream (worst case == R5).
//     Fixes R8's exec-divergence regression (quarter-wave trip counts).

constexpr int N_NODES = 50000;
constexpr int N_EDGES = 1600000;
constexpr int D = 128;

constexpr int NBUCK = 392;                    // ceil(50176/128) node-range buckets
constexpr int BCAP  = 6144;                   // capacity per bucket (mean 4082)
constexpr int EPB   = 4096;                   // edges per block in count/scatter
constexpr int CS_BLOCKS = (N_EDGES + EPB - 1) / EPB;   // 391
constexpr int GC_STRIDE = 16;                 // 64B pad: 1 atomic counter per sector

constexpr int NT  = 8;                        // src tiles (8192 nodes each)
constexpr int TSH = 13;                       // tile = src >> 13

typedef __bf16 bf16x8 __attribute__((ext_vector_type(8)));
typedef float f32x4 __attribute__((ext_vector_type(4)));
union U8 { bf16x8 v; __bf16 e[8]; };

// ---------------- zero ----------------------------------------------------
__global__ void zero1(int* __restrict__ a, int n) {
    int i = blockIdx.x * blockDim.x + threadIdx.x;
    if (i < n) a[i] = 0;
}

// ---------------- bucket count + scatter ----------------------------------
// Per block: LDS hist over 392 buckets (dst>>7), reserve space per bucket with
// ONE padded global atomic, then write packed (dstlow<<16 | src) to bucketbuf.
__global__ __launch_bounds__(256) void bucket_count_scatter(
        const int* __restrict__ dst, const int* __restrict__ src,
        int* __restrict__ gcursor, int* __restrict__ bucketbuf) {
    __shared__ int hcnt[NBUCK];
    __shared__ int hbase[NBUCK];
    const int tid = threadIdx.x;
    for (int i = tid; i < NBUCK; i += 256) hcnt[i] = 0;
    __syncthreads();

    const int e0 = blockIdx.x * EPB;
    int d[16], lp[16];
    #pragma unroll
    for (int t = 0; t < 16; ++t) {
        const int e = e0 + t * 256 + tid;
        if (e < N_EDGES) {
            d[t] = dst[e];
            lp[t] = atomicAdd(&hcnt[d[t] >> 7], 1);   // LDS atomic, local pos
        } else {
            d[t] = 0; lp[t] = -1;
        }
    }
    __syncthreads();

    for (int i = tid; i < NBUCK; i += 256) {
        const int c = hcnt[i];
        hbase[i] = c ? atomicAdd(&gcursor[i * GC_STRIDE], c) : 0;  // 1/(blk,bucket)
    }
    __syncthreads();

    #pragma unroll
    for (int t = 0; t < 16; ++t) {
        const int e = e0 + t * 256 + tid;
        if (e < N_EDGES) {
            const int s  = src[e];
            const int bk = d[t] >> 7;
            const int p  = hbase[bk] + lp[t];
            if (p < BCAP)
                bucketbuf[bk * BCAP + p] = ((d[t] & 127) << 16) | s;
        }
    }
}

// ---------------- scan bucket totals -> bases ------------------------------
__global__ void bucket_scan(const int* __restrict__ gcursor,
                            int* __restrict__ bucket_base) {
    __shared__ int wsum[8], wpre[8];
    const int t = threadIdx.x;                // 512 threads, 8 waves
    const int lane = t & 63, w = t >> 6;
    int v = 0;
    if (t < NBUCK) { v = gcursor[t * GC_STRIDE]; if (v > BCAP) v = BCAP; }
    int x = v;
    #pragma unroll
    for (int off = 1; off < 64; off <<= 1) {
        int tt = __shfl_up(x, off, 64);
        if (lane >= off) x += tt;
    }
    if (lane == 63) wsum[w] = x;
    __syncthreads();
    if (t < 8) {
        int s = wsum[t], y = s;
        #pragma unroll
        for (int off = 1; off < 8; off <<= 1) {
            int tt = __shfl_up(y, off, 64);
            if (t >= off) y += tt;
        }
        wpre[t] = y - s;
    }
    __syncthreads();
    if (t < NBUCK) bucket_base[t] = wpre[w] + (x - v);
}

// ---------------- per-bucket CSR finalize (tile-sorted, NT=8) --------------
// One block per bucket: LDS hist of 128 nodes x 8 src-tiles -> global offsets
// tp[node*8+t] + inv_deg, then LDS-cursor scatter of esrc grouped by
// (node, tile). Result: esrc globally sorted by (dst, src>>13).
__global__ __launch_bounds__(256) void bucket_csr(
        const int* __restrict__ gcursor, const int* __restrict__ bucket_base,
        const int* __restrict__ bucketbuf, int* __restrict__ tp,
        float* __restrict__ inv_deg, int* __restrict__ esrc) {
    __shared__ int h[1024];
    __shared__ int cur[1024];
    __shared__ int wsum[4], wpre[4];
    const int bk = blockIdx.x, tid = threadIdx.x;
    int cnt = gcursor[bk * GC_STRIDE];
    if (cnt > BCAP) cnt = BCAP;
    const int base = bucket_base[bk];
    #pragma unroll
    for (int k = 0; k < 4; ++k) h[tid * 4 + k] = 0;
    __syncthreads();

    const int* bb = bucketbuf + (size_t)bk * BCAP;
    for (int i = tid; i < cnt; i += 256) {
        const int p = bb[i];
        atomicAdd(&h[((p >> 16) << 3) | ((p & 0xFFFF) >> TSH)], 1);
    }
    __syncthreads();

    if (tid < 128) {
        int dg = 0;
        #pragma unroll
        for (int k = 0; k < 8; ++k) dg += h[tid * 8 + k];
        inv_deg[bk * 128 + tid] = 1.0f / fmaxf((float)dg, 1.0f);
    }

    // exclusive scan of 1024 counters (4 per thread)
    const int v0 = h[tid * 4], v1 = h[tid * 4 + 1];
    const int v2 = h[tid * 4 + 2], v3 = h[tid * 4 + 3];
    const int s = v0 + v1 + v2 + v3;
    int x = s;
    const int lane = tid & 63, w = tid >> 6;
    #pragma unroll
    for (int off = 1; off < 64; off <<= 1) {
        int tt = __shfl_up(x, off, 64);
        if (lane >= off) x += tt;
    }
    if (lane == 63) wsum[w] = x;
    __syncthreads();
    if (tid == 0) {
        int a = 0;
        #pragma unroll
        for (int k = 0; k < 4; ++k) { wpre[k] = a; a += wsum[k]; }
    }
    __syncthreads();
    const int e0 = wpre[w] + (x - s);
    const int e1 = e0 + v0, e2 = e1 + v1, e3 = e2 + v2;
    cur[tid * 4] = e0; cur[tid * 4 + 1] = e1;
    cur[tid * 4 + 2] = e2; cur[tid * 4 + 3] = e3;
    int* tpo = tp + (size_t)bk * 1024 + tid * 4;
    tpo[0] = base + e0; tpo[1] = base + e1; tpo[2] = base + e2; tpo[3] = base + e3;
    __syncthreads();

    for (int i = tid; i < cnt; i += 256) {
        const int p = bb[i];
        const int f = ((p >> 16) << 3) | ((p & 0xFFFF) >> TSH);
        esrc[base + atomicAdd(&cur[f], 1)] = p & 0xFFFF;
    }
}

// ---------------- pack W into MFMA B-fragment order, hi+lo ---------------
__global__ void pack_w(const float* __restrict__ w0, const float* __restrict__ w1,
                       const float* __restrict__ w2, const float* __restrict__ w3,
                       const float* __restrict__ w4, const float* __restrict__ w5,
                       __bf16* __restrict__ outbase) {
    const float* ws[6] = {w0, w1, w2, w3, w4, w5};
    const float* W = ws[blockIdx.y];
    __bf16* o = outbase + (size_t)blockIdx.y * 32768;
    int idx = blockIdx.x * 256 + threadIdx.x;   // 0..16383
    int t = idx & 7;
    int lane = (idx >> 3) & 63;
    int ks = (idx >> 9) & 3;
    int jt = idx >> 11;
    int j = jt * 16 + (lane & 15);
    int k = ks * 32 + (lane >> 4) * 8 + t;
    float w = W[j * D + k];
    __bf16 hi = (__bf16)w;
    o[idx] = hi;
    o[16384 + idx] = (__bf16)(w - (float)hi);
}

// ---------------- dual GEMM: y = h@Ws^T + b (fp32), z = h@Wn^T (bf16) ----
__global__ __launch_bounds__(256) void dual_gemm(
        const float* __restrict__ h, const __bf16* __restrict__ Bs,
        const __bf16* __restrict__ Bn, const float* __restrict__ bias,
        float* __restrict__ y_self, __bf16* __restrict__ z) {
    const int wave = threadIdx.x >> 6;
    const int lane = threadIdx.x & 63;
    const int tile = blockIdx.x * 4 + wave;
    if (tile >= N_NODES / 16) return;
    const int n0 = tile * 16;
    const int row = n0 + (lane & 15);
    const int koff = (lane >> 4) * 8;

    U8 ahi[4], alo[4];
    #pragma unroll
    for (int ks = 0; ks < 4; ++ks) {
        const float* p = h + (size_t)row * D + ks * 32 + koff;
        float f[8];
        *(f32x4*)&f[0] = *(const f32x4*)p;
        *(f32x4*)&f[4] = *(const f32x4*)(p + 4);
        #pragma unroll
        for (int t = 0; t < 8; ++t) {
            __bf16 hi = (__bf16)f[t];
            ahi[ks].e[t] = hi;
            alo[ks].e[t] = (__bf16)(f[t] - (float)hi);
        }
    }

    const int jcol = lane & 15;
    const int r0 = (lane >> 4) * 4;

    #pragma unroll 2
    for (int jt = 0; jt < 8; ++jt) {
        f32x4 accS = {0.f, 0.f, 0.f, 0.f};
        f32x4 accN = {0.f, 0.f, 0.f, 0.f};
        #pragma unroll
        for (int ks = 0; ks < 4; ++ks) {
            const size_t off = (((size_t)jt * 4 + ks) * 64 + lane) * 8;
            bf16x8 wsh = *(const bf16x8*)(Bs + off);
            bf16x8 wsl = *(const bf16x8*)(Bs + 16384 + off);
            bf16x8 wnh = *(const bf16x8*)(Bn + off);
            bf16x8 wnl = *(const bf16x8*)(Bn + 16384 + off);
            accS = __builtin_amdgcn_mfma_f32_16x16x32_bf16(ahi[ks].v, wsh, accS, 0, 0, 0);
            accS = __builtin_amdgcn_mfma_f32_16x16x32_bf16(alo[ks].v, wsh, accS, 0, 0, 0);
            accS = __builtin_amdgcn_mfma_f32_16x16x32_bf16(ahi[ks].v, wsl, accS, 0, 0, 0);
            accN = __builtin_amdgcn_mfma_f32_16x16x32_bf16(ahi[ks].v, wnh, accN, 0, 0, 0);
            accN = __builtin_amdgcn_mfma_f32_16x16x32_bf16(alo[ks].v, wnh, accN, 0, 0, 0);
            accN = __builtin_amdgcn_mfma_f32_16x16x32_bf16(ahi[ks].v, wnl, accN, 0, 0, 0);
        }
        const int j = jt * 16 + jcol;
        const float bj = bias[j];
        #pragma unroll
        for (int r = 0; r < 4; ++r) {
            const size_t n = n0 + r0 + r;
            y_self[n * D + j] = accS[r] + bj;
            z[n * D + j] = (__bf16)accN[r];
        }
    }
}

// ---------------- aggregate z (bf16) + add y_self (+relu) ----------------
// R5 structure verbatim: one wave per node; 4 edge slots x 16 lanes x 16B
// chunks of the 256B row; wave-uniform trip counts; 16 loads in flight.
// Only change: r0/r1 come from tp (tile-sorted edge list boundaries).
__global__ __launch_bounds__(256) void agg_add(
        const __bf16* __restrict__ z, const int* __restrict__ esrc,
        const int* __restrict__ tp, const float* __restrict__ inv_deg,
        const float* __restrict__ y_self, float* __restrict__ out, int do_relu) {
    const int n = blockIdx.x * 4 + (threadIdx.x >> 6);
    const int lane = threadIdx.x & 63;
    const int s = lane >> 4;
    const int c = lane & 15;
    const int r0 = tp[n * NT], r1 = tp[(n + 1) * NT];

    float acc[8] = {0.f, 0.f, 0.f, 0.f, 0.f, 0.f, 0.f, 0.f};
    int e = r0 + s;
    for (; e + 12 < r1; e += 16) {
        int i0 = esrc[e], i1 = esrc[e + 4], i2 = esrc[e + 8], i3 = esrc[e + 12];
        U8 v0, v1, v2, v3;
        v0.v = *(const bf16x8*)(z + (size_t)i0 * D + c * 8);
        v1.v = *(const bf16x8*)(z + (size_t)i1 * D + c * 8);
        v2.v = *(const bf16x8*)(z + (size_t)i2 * D + c * 8);
        v3.v = *(const bf16x8*)(z + (size_t)i3 * D + c * 8);
        #pragma unroll
        for (int t = 0; t < 8; ++t)
            acc[t] += ((float)v0.e[t] + (float)v1.e[t]) + ((float)v2.e[t] + (float)v3.e[t]);
    }
    for (; e < r1; e += 4) {
        U8 v0;
        v0.v = *(const bf16x8*)(z + (size_t)esrc[e] * D + c * 8);
        #pragma unroll
        for (int t = 0; t < 8; ++t) acc[t] += (float)v0.e[t];
    }
    #pragma unroll
    for (int t = 0; t < 8; ++t) acc[t] += __shfl_down(acc[t], 32, 64);
    #pragma unroll
    for (int t = 0; t < 8; ++t) acc[t] += __shfl_down(acc[t], 16, 64);

    if (lane < 16) {
        const float idg = inv_deg[n];
        const float* yp = y_self + (size_t)n * D + c * 8;
        f32x4 y0 = *(const f32x4*)yp;
        f32x4 y1 = *(const f32x4*)(yp + 4);
        float o[8];
        #pragma unroll
        for (int t = 0; t < 4; ++t) o[t] = y0[t] + acc[t] * idg;
        #pragma unroll
        for (int t = 0; t < 4; ++t) o[4 + t] = y1[t] + acc[4 + t] * idg;
        if (do_relu) {
            #pragma unroll
            for (int t = 0; t < 8; ++t) o[t] = fmaxf(o[t], 0.f);
        }
        float* op = out + (size_t)n * D + c * 8;
        *(f32x4*)op = *(f32x4*)&o[0];
        *(f32x4*)(op + 4) = *(f32x4*)&o[4];
    }
}

extern "C" void kernel_launch(void* const* d_in, const int* in_sizes, int n_in,
                              void* d_out, int out_size, void* d_ws, size_t ws_size,
                              hipStream_t stream) {
    const float* x   = (const float*)d_in[0];
    const int* src   = (const int*)d_in[1];
    const int* dst   = (const int*)d_in[2];
    const float* Wn1 = (const float*)d_in[3];
    const float* Ws1 = (const float*)d_in[4];
    const float* b1  = (const float*)d_in[5];
    const float* Wn2 = (const float*)d_in[6];
    const float* Ws2 = (const float*)d_in[7];
    const float* b2  = (const float*)d_in[8];
    const float* Wn3 = (const float*)d_in[9];
    const float* Ws3 = (const float*)d_in[10];
    const float* b3  = (const float*)d_in[11];
    float* out = (float*)d_out;

    char* w = (char*)d_ws;
    float* inv_deg     = (float*)w;             w += 50176 * 4;
    int* tp            = (int*)w;               w += (size_t)NBUCK * 1024 * 4;  // per-(node,tile)
    int* gcursor       = (int*)w;               w += NBUCK * GC_STRIDE * 4;
    int* bucket_base   = (int*)w;               w += 512 * 4;
    int* esrc          = (int*)w;               w += (size_t)N_EDGES * 4;
    __bf16* Bpk        = (__bf16*)w;            w += 6 * 32768 * 2;
    __bf16* zbuf       = (__bf16*)w;            w += (size_t)50176 * D * 2;
    float* bufA        = (float*)w;             // N*D floats

    // bucketbuf (392*6144*4B = 9.63MB) aliases zbuf (12.8MB): consumed by
    // bucket_csr before dual_gemm first writes zbuf (stream-ordered).
    int* bucketbuf = (int*)zbuf;

    const __bf16* PWs1 = Bpk + 0 * 32768, *PWn1 = Bpk + 1 * 32768;
    const __bf16* PWs2 = Bpk + 2 * 32768, *PWn2 = Bpk + 3 * 32768;
    const __bf16* PWs3 = Bpk + 4 * 32768, *PWn3 = Bpk + 5 * 32768;

    // ---- CSR build (bucketed, tile-sorted) ----
    zero1<<<(NBUCK * GC_STRIDE + 255) / 256, 256, 0, stream>>>(gcursor, NBUCK * GC_STRIDE);
    bucket_count_scatter<<<CS_BLOCKS, 256, 0, stream>>>(dst, src, gcursor, bucketbuf);
    bucket_scan<<<1, 512, 0, stream>>>(gcursor, bucket_base);
    bucket_csr<<<NBUCK, 256, 0, stream>>>(gcursor, bucket_base, bucketbuf,
                                          tp, inv_deg, esrc);

    // ---- pack weights (order: Ws1,Wn1,Ws2,Wn2,Ws3,Wn3) ----
    pack_w<<<dim3(64, 6), 256, 0, stream>>>(Ws1, Wn1, Ws2, Wn2, Ws3, Wn3, Bpk);

    const int ggrid = (N_NODES / 16 + 3) / 4;   // 782 blocks x 4 waves
    const int agrid = N_NODES / 4;              // 12500 blocks x 4 waves

    // layer 1: h=x -> bufA (relu)
    dual_gemm<<<ggrid, 256, 0, stream>>>(x, PWs1, PWn1, b1, bufA, zbuf);
    agg_add<<<agrid, 256, 0, stream>>>(zbuf, esrc, tp, inv_deg, bufA, bufA, 1);

    // layer 2: h=bufA -> d_out (relu)
    dual_gemm<<<ggrid, 256, 0, stream>>>(bufA, PWs2, PWn2, b2, out, zbuf);
    agg_add<<<agrid, 256, 0, stream>>>(zbuf, esrc, tp, inv_deg, out, out, 1);

    // layer 3: h=d_out -> d_out (no relu), y_self staged in bufA
    dual_gemm<<<ggrid, 256, 0, stream>>>(out, PWs3, PWn3, b3, bufA, zbuf);
    agg_add<<<agrid, 256, 0, stream>>>(zbuf, esrc, tp, inv_deg, bufA, out, 0);
}